// Round 6
// baseline (390.239 us; speedup 1.0000x reference)
//
#include <hip/hip_runtime.h>

#define NSHOTS 4
#define NT     512
#define NZ     256
#define NX     256
#define NRECS  128

static constexpr float DTf    = 0.001f;
static constexpr float INVDH2 = 1.0f / (10.0f * 10.0f);

#define KSTEPS 16                 // fused steps per phase
#define TILE   32                 // interior tile edge
#define RPT    8                  // ext rows per thread
#define NWAVES 8
#define BLOCK  512
#define NWG    (NSHOTS * 64)      // 256 WGs, one per CU (co-resident)
#define NPHASE (NT / KSTEPS)      // 32
#define NPAIR  4                  // field pairs (pipeline slip = NPAIR-1)
#define LSTRIDE 32                // dwords between flags (128 B)
#define FCNT   (NSHOTS * NZ * NX) // floats per field (262144)

// lane i <- lane i-1 (left x-neighbor); lane 0 gets 0 (matches zero pad)
__device__ __forceinline__ float nbr_left(float v) {
  return __int_as_float(__builtin_amdgcn_update_dpp(
      0, __float_as_int(v), 0x138 /*WAVE_SHR1*/, 0xf, 0xf, false));
}
// lane i <- lane i+1 (right x-neighbor); lane 63 gets 0
__device__ __forceinline__ float nbr_right(float v) {
  return __int_as_float(__builtin_amdgcn_update_dpp(
      0, __float_as_int(v), 0x130 /*WAVE_SHL1*/, 0xf, 0xf, false));
}

// LLC-coherent (cross-XCD) access: agent-scope relaxed -> sc0 sc1.
__device__ __forceinline__ float gload(const float* p) {
  return __hip_atomic_load(p, __ATOMIC_RELAXED, __HIP_MEMORY_SCOPE_AGENT);
}
__device__ __forceinline__ void gstore(float* p, float v) {
  __hip_atomic_store(p, v, __ATOMIC_RELAXED, __HIP_MEMORY_SCOPE_AGENT);
}
__device__ __forceinline__ unsigned fload(const unsigned* p) {
  return __hip_atomic_load(p, __ATOMIC_RELAXED, __HIP_MEMORY_SCOPE_AGENT);
}
__device__ __forceinline__ void fstore(unsigned* p, unsigned v) {
  __hip_atomic_store(p, v, __ATOMIC_RELAXED, __HIP_MEMORY_SCOPE_AGENT);
}

__global__ __launch_bounds__(BLOCK, 4) void wave_p2p4(
    float* __restrict__ fld,                            // NPAIR pairs of fields
    const float* __restrict__ vp, const float* __restrict__ xwav,
    const int* __restrict__ src_z, const int* __restrict__ src_x,
    const int* __restrict__ rec_z, const int* __restrict__ rec_x,
    float* __restrict__ out,                            // [NSHOTS*NT*NRECS]
    unsigned* __restrict__ bar)                         // wFlag[NWG], rFlag[NWG] @128B stride
{
  const int bid  = blockIdx.x;
  const int s    = bid >> 6;
  const int tz   = (bid >> 3) & 7;
  const int tx   = bid & 7;
  const int tid  = threadIdx.x;
  const int w    = tid >> 6;
  const int lane = tid & 63;

  const int gz0 = tz * TILE - KSTEPS;
  const int gx0 = tx * TILE - KSTEPS;
  const int gx  = gx0 + lane;
  const int zb  = w * RPT;

  __shared__ float haloTop[2][NWAVES][64];
  __shared__ float haloBot[2][NWAVES][64];
  __shared__ float recTile[2][TILE][TILE + 1];
  __shared__ int   cntS;
  __shared__ int   lzA[NRECS], lxA[NRECS];
  __shared__ unsigned pkA[NRECS];

  // ---- prologue: receiver compaction + masks ----
  if (tid == 0) cntS = 0;
  __syncthreads();
  if (tid < NRECS) {
    const int lz = rec_z[s * NRECS + tid] - tz * TILE;
    const int lx = rec_x[s * NRECS + tid] - tx * TILE;
    lzA[tid] = lz; lxA[tid] = lx;
    if ((unsigned)lz < (unsigned)TILE && (unsigned)lx < (unsigned)TILE) {
      const int k = atomicAdd(&cntS, 1);
      pkA[k] = (unsigned)tid | ((unsigned)lz << 8) | ((unsigned)lx << 16);
    }
  }
  __syncthreads();
  const int nRec = cntS;
  int myR = 0, myLz = 0, myLx = 0;
  if (tid < nRec) {
    const unsigned p = pkA[tid];
    myR = p & 255; myLz = (p >> 8) & 31; myLx = (p >> 16) & 31;
  }
  const bool wbRow = (w >= 2 && w < 6) && (lane >= KSTEPS && lane < KSTEPS + TILE);
  const int  ilz   = (w - 2) * RPT;
  const int  ilx   = lane - KSTEPS;
  unsigned recMask = 0;
  if (wbRow) {
    for (int r = 0; r < NRECS; ++r)
      if (lxA[r] == ilx && (unsigned)(lzA[r] - ilz) < (unsigned)RPT)
        recMask |= 1u << (lzA[r] - ilz);
  }

  // neighbor bid for flag lanes (tid<8 -> the 8 surrounding tiles, same shot)
  int nb = -1;
  if (tid < 8) {
    const int k  = (tid < 4) ? tid : tid + 1;   // skip center of 3x3
    const int dz = k / 3 - 1, dx = k % 3 - 1;
    const int qz = tz + dz, qx = tx + dx;
    if ((unsigned)qz < 8u && (unsigned)qx < 8u)
      nb = (s << 6) | (qz << 3) | qx;
  }
  unsigned* wF = bar;
  unsigned* rF = bar + (size_t)NWG * LSTRIDE;

  auto pollGE = [&](unsigned* base, unsigned target) {
    if (nb >= 0) {
      while (fload(base + (size_t)nb * LSTRIDE) < target)
        __builtin_amdgcn_s_sleep(1);
    }
  };

  // source mask
  const int slz = src_z[s] - gz0;
  const int slx = src_x[s] - gx0;
  const bool srcMine = (slx == lane) && ((unsigned)(slz - zb) < (unsigned)RPT);
  const int  srcI = slz - zb;
  float srcM[RPT];
  #pragma unroll
  for (int i = 0; i < RPT; ++i) srcM[i] = (srcMine && srcI == i) ? 1.0f : 0.0f;

  // phase-invariant per-row addresses/validity (hoisted) + c2 in registers
  const bool xok = (unsigned)gx < (unsigned)NX;
  int   offRow[RPT];
  bool  okRow[RPT];
  float a[RPT], b[RPT], c2[RPT];
  #pragma unroll
  for (int i = 0; i < RPT; ++i) {
    const int gz = gz0 + zb + i;
    const bool ok = xok && ((unsigned)gz < (unsigned)NZ);
    okRow[i]  = ok;
    offRow[i] = ok ? ((s * NZ + gz) * NX + gx) : 0;
    float v = ok ? vp[gz * NX + gx] : 0.0f;
    v *= DTf;
    c2[i] = v * v * INVDH2;
    a[i] = 0.0f; b[i] = 0.0f;
  }

  #pragma unroll 1
  for (int ph = 0; ph < NPHASE; ++ph) {
    const int t0 = ph * KSTEPS;

    if (ph > 0) {
      // wait: all 8 neighbors finished writeback of phase ph-1
      pollGE(wF, (unsigned)ph);
      __syncthreads();
      // reload ghost region (interior threads keep a,b in registers)
      const float* rc = fld + (size_t)(((ph - 1) & (NPAIR - 1)) * 2) * FCNT;
      const float* rp = rc + FCNT;
      if (!wbRow) {
        #pragma unroll
        for (int i = 0; i < RPT; ++i) {
          a[i] = okRow[i] ? gload(rc + offRow[i]) : 0.0f;
          b[i] = okRow[i] ? gload(rp + offRow[i]) : 0.0f;
        }
      }
      __builtin_amdgcn_s_waitcnt(0);     // my reload actually read memory
      __syncthreads();
      if (tid == 0) fstore(rF + (size_t)bid * LSTRIDE, (unsigned)ph);
    }

    // 16 source amps via 4 vector loads (t0 is 64B-aligned into xwav row)
    float amp[KSTEPS];
    {
      const float4* xw4 = (const float4*)(xwav + s * NT + t0);
      #pragma unroll
      for (int q = 0; q < KSTEPS / 4; ++q) {
        const float4 v = xw4[q];
        amp[4 * q + 0] = (v.x * DTf) * DTf;
        amp[4 * q + 1] = (v.y * DTf) * DTf;
        amp[4 * q + 2] = (v.z * DTf) * DTf;
        amp[4 * q + 3] = (v.w * DTf) * DTf;
      }
    }

    float recv[KSTEPS];

    auto do_step = [&](float (&cur)[RPT], float (&nxt)[RPT], int tau) {
      const int pb = tau & 1;
      haloTop[pb][w][lane] = cur[0];
      haloBot[pb][w][lane] = cur[RPT - 1];
      __syncthreads();
      if (tau > 0 && tid < nRec) recv[tau - 1] = recTile[1 - pb][myLz][myLx];
      const float up0 = (w > 0)          ? haloBot[pb][w - 1][lane] : 0.0f;
      const float dn7 = (w < NWAVES - 1) ? haloTop[pb][w + 1][lane] : 0.0f;
      #pragma unroll
      for (int i = 0; i < RPT; ++i) {
        const float c  = cur[i];
        const float up = (i == 0)       ? up0 : cur[i - 1];
        const float dn = (i == RPT - 1) ? dn7 : cur[i + 1];
        const float lf = nbr_left(c);
        const float rt = nbr_right(c);
        const float sum = (up + dn) + (lf + rt);
        const float lap = __builtin_fmaf(-4.0f, c, sum);
        float v = __builtin_fmaf(2.0f, c, -nxt[i]);
        v = __builtin_fmaf(c2[i], lap, v);
        v = __builtin_fmaf(srcM[i], amp[tau], v);
        nxt[i] = v;
      }
      if (recMask) {
        #pragma unroll
        for (int i = 0; i < RPT; ++i)
          if (recMask & (1u << i)) recTile[pb][ilz + i][ilx] = nxt[i];
      }
    };

    #pragma unroll
    for (int h = 0; h < KSTEPS / 2; ++h) {
      do_step(a, b, 2 * h);
      do_step(b, a, 2 * h + 1);
    }

    // wait: neighbors consumed the pair we're about to overwrite (slip 3)
    if (ph >= NPAIR && ph != NPHASE - 1) pollGE(rF, (unsigned)(ph - (NPAIR - 1)));
    __syncthreads();   // recTile[1] ready + overwrite permission WG-wide
    if (tid < nRec) recv[KSTEPS - 1] = recTile[1][myLz][myLx];

    // receiver flush (normal cached stores; read only after kernel end)
    if (tid < nRec) {
      #pragma unroll
      for (int t = 0; t < KSTEPS; ++t)
        out[(s * NT + (t0 + t)) * NRECS + myR] = recv[t];
    }

    if (ph != NPHASE - 1) {
      // interior writeback (LLC-coherent)
      float* wc = fld + (size_t)((ph & (NPAIR - 1)) * 2) * FCNT;
      float* wp = wc + FCNT;
      if (wbRow) {
        #pragma unroll
        for (int i = 0; i < RPT; ++i) {
          gstore(wc + offRow[i], a[i]);
          gstore(wp + offRow[i], b[i]);
        }
      }
      __builtin_amdgcn_s_waitcnt(0);   // stores ack'd at LLC (per wave)
      __syncthreads();                 // whole WG drained
      if (tid == 0) fstore(wF + (size_t)bid * LSTRIDE, (unsigned)(ph + 1));
    }
  }
}

extern "C" void kernel_launch(void* const* d_in, const int* in_sizes, int n_in,
                              void* d_out, int out_size, void* d_ws, size_t ws_size,
                              hipStream_t stream) {
  const float* x     = (const float*)d_in[0];
  const float* vp    = (const float*)d_in[1];
  const int*   src_z = (const int*)d_in[2];
  const int*   src_x = (const int*)d_in[3];
  const int*   rec_z = (const int*)d_in[4];
  const int*   rec_x = (const int*)d_in[5];
  float* out = (float*)d_out;

  float* ws = (float*)d_ws;
  float* fld = ws;                                   // NPAIR*2 fields = 8 MB
  unsigned* bar = (unsigned*)(ws + (size_t)NPAIR * 2 * FCNT);

  // zero the p2p flags (wFlag + rFlag, 128B-strided)
  hipMemsetAsync(bar, 0, 2 * (size_t)NWG * LSTRIDE * sizeof(unsigned), stream);

  wave_p2p4<<<dim3(NWG), dim3(BLOCK), 0, stream>>>(
      fld, vp, x, src_z, src_x, rec_z, rec_x, out, bar);
}